// Round 10
// baseline (110.991 us; speedup 1.0000x reference)
//
#include <hip/hip_runtime.h>

#define K    5
#define KK   25
#define H    160
#define W    160
#define C    64
#define BS   4
#define HW   (H * W)

#define TX   32          // tile width (pixels)
#define TY   8           // tile height (rows)
#define CPB  8           // channels per block
#define CPW  2           // channels per thread
#define BLK  256

#define FR   (TY + 4)    // fm rows staged = 12
#define FS   44          // fm LDS row stride. With b128 window reads at col 4qx+4,
                         // starts = (12ty+4qx) mod 32 = 8 disjoint 4-bank windows
                         // x depth 8 = b128 structural minimum -> conflict-free.
                         // (R6's conflicts came from b64/float2 reads, not FS=44.)
#define WLS  36          // weight LDS row stride: starts 4(ty+qx) mod 32, disjoint
                         // 4-bank windows, b128 structural minimum.

// R10: weights join fm in LDS. R9's block issued 123 wave-VMEM instrs, 100 of
// them weight loads DUPLICATED 4x across the block's waves (waves differ only
// in channel slot), and the in-loop global weight latency was the dominant
// per-wave stall (R8's 1-row prefetch couldn't cover it). Now: one cooperative
// staging phase (fm 15 + weights 25 + stores 8 = 48 wave-VMEM/block, 2.6x cut),
// single barrier, and a compute loop that touches ONLY LDS + FMAs. fm tile is
// staged shifted +2 cols so windows are 16B-aligned 2x b128 per channel-row.
// LDS 45.7KB -> 3 blocks = 12 waves/CU; acceptable since per-wave stalls are
// now structurally small. No min-waves launch_bounds (R3/R4: cap => spill).
__global__ __launch_bounds__(BLK) void kconv_kernel(
    const float* __restrict__ fm,
    const float* __restrict__ kern,
    const int*  __restrict__ dil,
    float* __restrict__ out)
{
    __shared__ float fmlds[CPB * FR * FS];   // 16896 B
    __shared__ float wlds[KK * TY * WLS];    // 28800 B  (total 45696 B)

    const int tid   = threadIdx.x;
    const int gxb   = blockIdx.x;
    const int x0    = (gxb >> 3) * TX;       // 5 spatial x-tiles
    const int cg    = gxb & 7;               // 8 channel groups, dispatch-adjacent (L2)
    const int y0    = blockIdx.y * TY;
    const int b     = blockIdx.z;
    const int cbase = cg * CPB;
    const int d     = dil[0];

    const int lane = tid & 63;
    const int qx   = lane & 7;        // x-quad within tile row
    const int ty   = lane >> 3;       // row within tile
    const int c0   = (tid >> 6) * CPW;   // {0,2,4,6}

    const int x = x0 + 4 * qx;
    const int y = y0 + ty;
    const float* kb = kern + (size_t)b * KK * HW + (size_t)y * W + x;

    if (d == 1) {
        // ---- stage fm tile: 8 ch x 12 rows x 10 float4, global cols x0-4..x0+35
        //      stored at LDS cols 2..41 (l = global - x0 + 6), OOB -> 0
        const float* fmb = fm + ((size_t)b * C + cbase) * HW;
        for (int idx = tid; idx < CPB * FR * 10; idx += BLK) {   // 960 float4
            const int ch  = idx / (FR * 10);
            const int rem = idx - ch * (FR * 10);
            const int r   = rem / 10;
            const int f4  = rem - r * 10;
            const int gy  = y0 - 2 + r;
            const int gxc = x0 - 4 + 4 * f4;   // 16B-aligned global; all-in or all-out
            float4 v = make_float4(0.f, 0.f, 0.f, 0.f);
            if (gy >= 0 && gy < H && gxc >= 0 && gxc < W)
                v = *(const float4*)(fmb + (size_t)ch * HW + (size_t)gy * W + gxc);
            float* dst = &fmlds[(ch * FR + r) * FS + 4 * f4 + 2];  // 8B-aligned
            *(float2*)dst       = make_float2(v.x, v.y);
            *(float2*)(dst + 2) = make_float2(v.z, v.w);
        }
        // ---- stage weights, pre-flipped: slot t = kern[b][24-t][tile]
        const float* kbase = kern + (size_t)b * KK * HW + (size_t)y0 * W + x0;
        for (int idx = tid; idx < KK * TY * 8; idx += BLK) {     // 1600 float4
            const int m   = idx / (TY * 8);
            const int rem = idx - m * (TY * 8);
            const int r   = rem / 8;
            const int f4  = rem - r * 8;
            const float4 v = *(const float4*)(kbase + (size_t)m * HW + (size_t)r * W + 4 * f4);
            *(float4*)&wlds[((KK - 1 - m) * TY + r) * WLS + 4 * f4] = v;  // 16B-aligned
        }
        __syncthreads();

        float acc[CPW][4];
#pragma unroll
        for (int c = 0; c < CPW; ++c)
#pragma unroll
            for (int p = 0; p < 4; ++p) acc[c][p] = 0.f;

#pragma unroll
        for (int i = 0; i < K; ++i) {
            // weights for this tap row: 5x b128 from LDS (flipped, no masking:
            // OOB fm is zero-filled in LDS)
            float wr[K][4];
#pragma unroll
            for (int j = 0; j < K; ++j) {
                const float4 wv = *(const float4*)&wlds[((i * K + j) * TY + ty) * WLS + 4 * qx];
                wr[j][0] = wv.x; wr[j][1] = wv.y; wr[j][2] = wv.z; wr[j][3] = wv.w;
            }
            // fm windows: per channel 8 floats = 2x aligned b128 (cols x-2..x+5)
            float win[CPW][8];
#pragma unroll
            for (int c = 0; c < CPW; ++c) {
                const float* base = &fmlds[((c0 + c) * FR + ty + i) * FS + 4 * qx + 4];
                const float4 lo = *(const float4*)base;
                const float4 hi = *(const float4*)(base + 4);
                win[c][0] = lo.x; win[c][1] = lo.y; win[c][2] = lo.z; win[c][3] = lo.w;
                win[c][4] = hi.x; win[c][5] = hi.y; win[c][6] = hi.z; win[c][7] = hi.w;
            }
#pragma unroll
            for (int c = 0; c < CPW; ++c)
#pragma unroll
                for (int j = 0; j < K; ++j)
#pragma unroll
                    for (int p = 0; p < 4; ++p)
                        acc[c][p] = fmaf(wr[j][p], win[c][p + j], acc[c][p]);
        }

        float* ob = out + ((size_t)b * C + cbase + c0) * HW + (size_t)y * W + x;
#pragma unroll
        for (int c = 0; c < CPW; ++c) {
            const float4 o = {acc[c][0], acc[c][1], acc[c][2], acc[c][3]};
            *(float4*)(ob + (size_t)c * HW) = o;
        }
    } else {
        // Generic-dilation fallback (never taken in this bench; d==1 there).
        const float* fb = fm  + ((size_t)b * C + cbase + c0) * HW;
        float*       ob = out + ((size_t)b * C + cbase + c0) * HW + (size_t)y * W + x;
#pragma unroll 1
        for (int p = 0; p < 4; ++p) {
            const int xx = x + p;
            float wgt[KK];
            int   offs[KK];
#pragma unroll 1
            for (int i = 0; i < K; ++i) {
                const int  yy  = y + (i - 2) * d;
                const bool yok = (yy >= 0) && (yy < H);
                const int  yc  = min(max(yy, 0), H - 1);
#pragma unroll 1
                for (int j = 0; j < K; ++j) {
                    const int  xc  = xx + (j - 2) * d;
                    const bool ok  = yok && (xc >= 0) && (xc < W);
                    const int  xcc = min(max(xc, 0), W - 1);
                    const int  t   = i * K + j;
                    wgt[t]  = ok ? kb[(size_t)(KK - 1 - t) * HW + p] : 0.f;
                    offs[t] = yc * W + xcc;
                }
            }
#pragma unroll 1
            for (int c = 0; c < CPW; ++c) {
                const float* fc = fb + (size_t)c * HW;
                float a2 = 0.f;
#pragma unroll 1
                for (int t = 0; t < KK; ++t) a2 = fmaf(wgt[t], fc[offs[t]], a2);
                ob[(size_t)c * HW + p] = a2;
            }
        }
    }
}

extern "C" void kernel_launch(void* const* d_in, const int* in_sizes, int n_in,
                              void* d_out, int out_size, void* d_ws, size_t ws_size,
                              hipStream_t stream)
{
    const float* fm   = (const float*)d_in[0];
    const float* kern = (const float*)d_in[1];
    const int*   dil  = (const int*)d_in[2];
    float*       out  = (float*)d_out;

    dim3 grid(8 * (W / TX), H / TY, BS);   // 40 x 20 x 4 = 3200 blocks
    kconv_kernel<<<grid, dim3(BLK), 0, stream>>>(fm, kern, dil, out);
}